// Round 9
// baseline (962.292 us; speedup 1.0000x reference)
//
#include <hip/hip_runtime.h>
#include <math.h>

#define BB 4

typedef __bf16 bf16x8 __attribute__((ext_vector_type(8)));
typedef float f32x4 __attribute__((ext_vector_type(4)));

__device__ inline ushort f2bf(float x) {
  uint u = __float_as_uint(x);
  uint r = (u + 0x7fffu + ((u >> 16) & 1u)) >> 16;
  return (ushort)r;
}
__device__ inline float bf2f(ushort h) { return __uint_as_float(((uint)h) << 16); }
__device__ inline bf16x8 as_bf(uint4 u) {
  union { uint4 u; bf16x8 b; } c;
  c.u = u;
  return c.b;
}

// ---------------- weight pre-pack: all layers -> bf16 uint4 in conv-LDS layout
struct WPtrs { const float* w[12]; };

#define WTOTAL 146560

__global__ void prep_w_all(WPtrs wp, uint4* __restrict__ wbH) {
  const int tK[12]    = {5,3,5,3,3,3,3,3,3,3,3,3};
  const int tCC[12]   = {8,16,8,8,16,8,16,16,16,16,8,8};
  const int tSP[12]   = {28,10,28,12,10,12,10,10,10,10,12,12};
  const int tcinR[12] = {96,96,3,24,48,48,96,96,48,48,24,24};
  const int tcinp[12] = {96,96,8,24,48,48,96,96,48,48,24,24};
  const int tcout[12] = {96,96,24,48,48,96,48,48,24,24,24,3};
  const int tgat[12]  = {1,1,1,1,1,1,1,1,1,1,1,0};
  const int toff[13]  = {0,64512,87552,89344,92800,98560,112384,123904,135424,139264,143104,145408,146560};
  for (int i = blockIdx.x * 256 + threadIdx.x; i < WTOTAL; i += gridDim.x * 256) {
    int L = 0;
    while (toff[L + 1] <= i) L++;
    int li = i - toff[L];
    int K = tK[L], CC = tCC[L], SPAD = tSP[L];
    int CH = CC >> 3;
    int SZ = SPAD * CH * 32;
    int nch = tcinp[L] / CC;
    int yb = li / (nch * SZ);
    int rem = li - yb * nch * SZ;
    int chunk = rem / SZ;
    int t = rem - chunk * SZ;
    int ci0 = chunk * CC;
    int co32 = t & 31, sh = t >> 5;
    int s = sh / CH, hh = sh - s * CH;
    int fr;
    bool ok;
    if (tgat[L]) {
      int coL = yb * 16 + (co32 & 15);
      ok = coL < tcout[L];
      fr = (co32 < 16) ? coL : tcout[L] + coL;
    } else {
      fr = yb * 32 + co32;
      ok = fr < tcout[L];
    }
    ok = ok && (s < K * K);
    const float* wgt = wp.w[L];
    union { ushort u[8]; uint4 v; } th;
#pragma unroll
    for (int j = 0; j < 8; j++) {
      int ci = ci0 + hh * 8 + j;
      float v = 0.f;
      if (ok && ci < tcinR[L]) v = wgt[((size_t)fr * tcinR[L] + ci) * (K * K) + s];
      th.u[j] = f2bf(v);
    }
    wbH[i] = th.v;
  }
}

// ---------------- xnow -> NHWC8 bf16 hi/lo (3 real + 5 zero channels) -------
__global__ void k_xnow(const float* __restrict__ x, const float* __restrict__ x2,
                       const float* __restrict__ mask,
                       ushort* __restrict__ outH, ushort* __restrict__ outL) {
  int idx = blockIdx.x * 256 + threadIdx.x;
  if (idx >= BB * 65536) return;
  int b = idx >> 16, r = idx & 65535;
  float m = mask[idx];
  union { ushort u[8]; uint4 v; } h, l;
#pragma unroll
  for (int c = 0; c < 8; c++) { h.u[c] = 0; l.u[c] = 0; }
#pragma unroll
  for (int c = 0; c < 3; c++) {
    size_t s = ((size_t)(b * 3 + c) << 16) + r;
    float v = x2[s] * m + x[s] * (1.f - m);
    ushort hh = f2bf(v);
    h.u[c] = hh;
    l.u[c] = f2bf(v - bf2f(hh));
  }
  *(uint4*)&outH[(size_t)idx * 8] = h.v;
  *(uint4*)&outL[(size_t)idx * 8] = l.v;
}

// ---------------- pm (NCHW f32, 96ch 64x64) -> NHWC96 hi/lo ----------------
__global__ void k_tr(const float* __restrict__ pm,
                     ushort* __restrict__ outH, ushort* __restrict__ outL) {
  int idx = blockIdx.x * 256 + threadIdx.x;
  if (idx >= BB * 4096) return;
  int b = idx >> 12, pix = idx & 4095;
#pragma unroll
  for (int g = 0; g < 12; g++) {
    union { ushort u[8]; uint4 v; } h, l;
#pragma unroll
    for (int j = 0; j < 8; j++) {
      float v = pm[(((size_t)b * 96 + g * 8 + j) << 12) + pix];
      ushort hh = f2bf(v);
      h.u[j] = hh;
      l.u[j] = f2bf(v - bf2f(hh));
    }
    *(uint4*)&outH[(size_t)idx * 96 + g * 8] = h.v;
    *(uint4*)&outL[(size_t)idx * 96 + g * 8] = l.v;
  }
}

// ---------------- MFMA implicit-GEMM conv, NHWC hi/lo acts, bf16 weights ----
template <int K, int STRIDE, int UP, int CC, int TH, int TW, int SPAD>
__global__ __launch_bounds__(256) void conv_mfma(
    const ushort* __restrict__ in1H, const ushort* __restrict__ in1L,
    const ushort* __restrict__ in2H, const ushort* __restrict__ in2L,
    int s1, int s2, int g1, int cinp,
    const uint4* __restrict__ wbH,
    const float* __restrict__ bias,
    ushort* __restrict__ outH, ushort* __restrict__ outL, float* __restrict__ outF,
    int Hin, int Win, int Hout, int Wout,
    int coutEff, int coutp, int act, int tilesX) {
  constexpr int CH = CC / 8;
  constexpr int GS = 4 / CH;
  constexpr int NGc = CC / 8;
  constexpr int CCp = (CC == 16) ? 24 : 8;
  constexpr int IH = (TH - 1) * STRIDE + K;
  constexpr int IW = (TW - 1) * STRIDE + K;
  constexpr int NF = (TH * TW) / 64;
  constexpr int NSC = SPAD / GS;
  constexpr int WSZ = SPAD * CH * 32;

  __shared__ ushort sInH[IH * IW * CCp];
  __shared__ ushort sInL[IH * IW * CCp];
  __shared__ uint4 sWH[WSZ];

  const int tid = threadIdx.x;
  const int lane = tid & 63, wv = tid >> 6;
  const int m = lane & 15, gg = lane >> 4;
  const int b = blockIdx.z;
  const int yb = blockIdx.y;
  const int tX = blockIdx.x % tilesX, tY = blockIdx.x / tilesX;
  const int pad = (K - 1) / 2;
  const int HinU = Hin << UP, WinU = Win << UP;
  const int oy0 = tY * TH * STRIDE - pad;
  const int ox0 = tX * TW * STRIDE - pad;
  const int gated = (act != 2);
  const int NG = cinp >> 3;
  const int nch = cinp / CC;
  const size_t HWin = (size_t)Hin * Win;

  f32x4 acc[2][NF];
#pragma unroll
  for (int i = 0; i < 2; i++)
#pragma unroll
    for (int j = 0; j < NF; j++) acc[i][j] = (f32x4){0.f, 0.f, 0.f, 0.f};

  for (int ci0 = 0; ci0 < cinp; ci0 += CC) {
    __syncthreads();
    // ---- stage input tile: pure vector copies ----
    for (int t = tid; t < IH * IW * NGc; t += 256) {
      int p = (NGc == 2) ? (t >> 1) : t;
      int g = (NGc == 2) ? (t & 1) : 0;
      int iy = p / IW, ix = p % IW;
      int gy = oy0 + iy, gx = ox0 + ix;
      int gi = (ci0 >> 3) + g;
      uint4 h = {0u, 0u, 0u, 0u}, l = {0u, 0u, 0u, 0u};
      if (gi < NG && gy >= 0 && gy < HinU && gx >= 0 && gx < WinU) {
        int sy = gy >> UP, sx = gx >> UP;
        size_t poff = (size_t)b * HWin + (size_t)sy * Win + sx;
        if (gi < g1) {
          size_t a = poff * s1 + gi * 8;
          h = *(const uint4*)&in1H[a];
          l = *(const uint4*)&in1L[a];
        } else {
          size_t a = poff * s2 + (gi - g1) * 8;
          h = *(const uint4*)&in2H[a];
          l = *(const uint4*)&in2L[a];
        }
      }
      int d = p * CCp + g * 8;
      *(uint4*)&sInH[d] = h;
      *(uint4*)&sInL[d] = l;
    }
    // ---- stage weights: coalesced copy from pre-packed buffer ----
    {
      const uint4* pH = wbH + ((size_t)yb * nch + (ci0 / CC)) * WSZ;
      for (int t = tid; t < WSZ; t += 256) sWH[t] = pH[t];
    }
    __syncthreads();
    // ---- compute ----
#pragma unroll
    for (int sc = 0; sc < NSC; sc++) {
      int sg = sc * GS + gg / CH;
      int hh = gg - (gg / CH) * CH;
      int s = (sg < K * K) ? sg : 0;
      int kh = s / K, kw = s - kh * K;
      bf16x8 ah[2], bh[NF], bl[NF];
#pragma unroll
      for (int mi = 0; mi < 2; mi++) {
        int ai = (sc * 4 + gg) * 32 + mi * 16 + m;
        ah[mi] = as_bf(sWH[ai]);
      }
#pragma unroll
      for (int ni = 0; ni < NF; ni++) {
        int pix = wv * (NF * 16) + ni * 16 + m;
        int py = pix >> 4, px = pix & 15;
        int li = ((py * STRIDE + kh) * IW + px * STRIDE + kw) * CCp + hh * 8;
        bh[ni] = as_bf(*(const uint4*)&sInH[li]);
        bl[ni] = as_bf(*(const uint4*)&sInL[li]);
      }
#pragma unroll
      for (int mi = 0; mi < 2; mi++)
#pragma unroll
        for (int ni = 0; ni < NF; ni++) {
          acc[mi][ni] = __builtin_amdgcn_mfma_f32_16x16x32_bf16(ah[mi], bh[ni], acc[mi][ni], 0, 0, 0);
          acc[mi][ni] = __builtin_amdgcn_mfma_f32_16x16x32_bf16(ah[mi], bl[ni], acc[mi][ni], 0, 0, 0);
        }
    }
  }
  // ---- epilogue ----
  const size_t HWout = (size_t)Hout * Wout;
  if (gated) {
    int co0 = yb * 16 + gg * 4;
    bool cov = co0 < coutEff;
    float bA[4], bG[4];
#pragma unroll
    for (int r = 0; r < 4; r++) {
      bA[r] = cov ? bias[co0 + r] : 0.f;
      bG[r] = cov ? bias[coutEff + co0 + r] : 0.f;
    }
#pragma unroll
    for (int ni = 0; ni < NF; ni++) {
      int pix = wv * (NF * 16) + ni * 16 + m;
      int py = pix >> 4, px = pix & 15;
      int gy = tY * TH + py, gx = tX * TW + px;
      if (!cov) continue;
      union { ushort u[4]; uint2 v; } oh, ol;
#pragma unroll
      for (int r = 0; r < 4; r++) {
        float a = acc[0][ni][r] + bA[r];
        float g = acc[1][ni][r] + bG[r];
        float aa = (act == 1) ? fmaxf(a, 0.f) : (a > 0.f ? a : expm1f(a));
        float o = aa * (1.f / (1.f + expf(-g)));
        ushort hh = f2bf(o);
        oh.u[r] = hh;
        ol.u[r] = f2bf(o - bf2f(hh));
      }
      size_t base = ((size_t)b * HWout + (size_t)gy * Wout + gx) * coutp + co0;
      *(uint2*)&outH[base] = oh.v;
      *(uint2*)&outL[base] = ol.v;
    }
  } else {
#pragma unroll
    for (int mi = 0; mi < 2; mi++)
#pragma unroll
      for (int ni = 0; ni < NF; ni++) {
        int pix = wv * (NF * 16) + ni * 16 + m;
        int py = pix >> 4, px = pix & 15;
        int gy = tY * TH + py, gx = tX * TW + px;
#pragma unroll
        for (int r = 0; r < 4; r++) {
          int co = yb * 32 + mi * 16 + gg * 4 + r;
          if (co >= coutEff) continue;
          float o = tanhf(acc[mi][ni][r] + bias[co]);
          outF[(size_t)(b * coutEff + co) * HWout + (size_t)gy * Wout + gx] = o;
        }
      }
  }
}

// ---------------- cp1 helpers ----------------
__global__ void k_mask_s(const float* __restrict__ mask, float* __restrict__ mask_s) {
  int idx = blockIdx.x * 256 + threadIdx.x;
  if (idx >= BB * 4096) return;
  int b = idx >> 12, r = idx & 4095;
  int i = r >> 6, j = r & 63;
  float s = 0.f;
  for (int u = 0; u < 4; u++)
    for (int v = 0; v < 4; v++)
      s += mask[(size_t)b * 65536 + (i * 4 + u) * 256 + (j * 4 + v)];
  mask_s[idx] = s * (1.f / 16.f);
}

__global__ void k_mm(const float* __restrict__ mask_s, float* __restrict__ mm) {
  int idx = blockIdx.x * 256 + threadIdx.x;
  if (idx >= BB * 1024) return;
  int b = idx >> 10, l = idx & 1023;
  int li = l >> 5, lj = l & 31;
  float s = 0.f;
  for (int dy = 0; dy < 4; dy++) {
    int row = 2 * li + dy - 1;
    if (row < 0 || row >= 64) continue;
    for (int dx = 0; dx < 4; dx++) {
      int col = 2 * lj + dx - 1;
      if (col < 0 || col >= 64) continue;
      s += mask_s[((size_t)b << 12) + row * 64 + col];
    }
  }
  mm[idx] = (s == 0.f) ? 1.f : 0.f;
}

// block per (b,l): LDS transpose, coalesced in & out. p = c*16 + dy*4 + dx.
__global__ __launch_bounds__(256) void extract_patches_bf(
    const ushort* __restrict__ xsH, const ushort* __restrict__ xsL,
    ushort* __restrict__ Phi, ushort* __restrict__ Plo) {
  int bl = blockIdx.x;
  int b = bl >> 10, l = bl & 1023;
  int li = l >> 5, lj = l & 31;
  __shared__ ushort sH[1536], sL[1536];
  int tid = threadIdx.x;
  for (int t = tid; t < 192; t += 256) {
    ((uint4*)sH)[t] = (uint4){0u, 0u, 0u, 0u};
    ((uint4*)sL)[t] = (uint4){0u, 0u, 0u, 0u};
  }
  __syncthreads();
  if (tid < 192) {
    int px = tid / 12, g = tid % 12;
    int dy = px >> 2, dx = px & 3;
    int row = 2 * li + dy - 1, col = 2 * lj + dx - 1;
    if (row >= 0 && row < 64 && col >= 0 && col < 64) {
      size_t a = ((((size_t)b << 12) + (row << 6) + col) * 96) + g * 8;
      union { uint4 v; ushort u[8]; } h, lo;
      h.v = *(const uint4*)&xsH[a];
      lo.v = *(const uint4*)&xsL[a];
#pragma unroll
      for (int j = 0; j < 8; j++) {
        int c = g * 8 + j;
        sH[c * 16 + px] = h.u[j];
        sL[c * 16 + px] = lo.u[j];
      }
    }
  }
  __syncthreads();
  size_t o = (size_t)bl * 1536;
  for (int t = tid; t < 192; t += 256) {
    ((uint4*)(Phi + o))[t] = ((uint4*)sH)[t];
    ((uint4*)(Plo + o))[t] = ((uint4*)sL)[t];
  }
}

__global__ void k_scale_bf(const ushort* __restrict__ Phi, const ushort* __restrict__ Plo,
                           const float* __restrict__ mm, float* __restrict__ scale) {
  int bl = blockIdx.x;
  const ushort* rh = Phi + (size_t)bl * 1536;
  const ushort* rl = Plo + (size_t)bl * 1536;
  int tid = threadIdx.x;
  float s = 0.f;
  for (int i = 0; i < 6; i++) {
    float v = bf2f(rh[tid + i * 256]) + bf2f(rl[tid + i * 256]);
    s += v * v;
  }
  __shared__ float red[256];
  red[tid] = s; __syncthreads();
  for (int t = 128; t > 0; t >>= 1) { if (tid < t) red[tid] += red[tid + t]; __syncthreads(); }
  if (tid == 0) scale[bl] = mm[bl] / fmaxf(sqrtf(red[0]), 1e-4f);
}

// ---------------- MFMA GEMM qk: 512 thr, K-chunk 64, XCD-local qTile --------
__global__ __launch_bounds__(512) void gemm_qk_mfma(
    const ushort* __restrict__ Phi, const ushort* __restrict__ Plo,
    const float* __restrict__ scale, float* __restrict__ S) {
  int b = blockIdx.z;
  int f = blockIdx.x + (blockIdx.y << 3);
  int qTile = (f & 7) * 128, lTile = (f >> 3) * 128;  // same qTile -> same XCD
  __shared__ uint4 sAh[1024], sAl[1024], sBh[1024], sBl[1024];

  int tid = threadIdx.x;
  int lane = tid & 63, w = tid >> 6;
  int wy = w >> 2, wx = w & 3;
  int m = lane & 15, gg = lane >> 4;

  f32x4 acc[4][2];
#pragma unroll
  for (int i = 0; i < 4; i++)
#pragma unroll
    for (int j = 0; j < 2; j++) acc[i][j] = (f32x4){0.f, 0.f, 0.f, 0.f};

  for (int k0 = 0; k0 < 1536; k0 += 64) {
    __syncthreads();
    for (int t = tid; t < 1024; t += 512) {
      int r = t >> 3, g = t & 7;
      int slot = (r << 3) + (g ^ (r & 7));
      size_t aoff = ((size_t)(b * 1024 + qTile + r)) * 1536 + k0;
      size_t boff = ((size_t)(b * 1024 + lTile + r)) * 1536 + k0;
      sAh[slot] = ((const uint4*)(Phi + aoff))[g];
      sAl[slot] = ((const uint4*)(Plo + aoff))[g];
      sBh[slot] = ((const uint4*)(Phi + boff))[g];
      sBl[slot] = ((const uint4*)(Plo + boff))[g];
    }
    __syncthreads();
#pragma unroll
    for (int c = 0; c < 2; c++) {
      bf16x8 ah[4], al[4], bh[2], bl[2];
#pragma unroll
      for (int i = 0; i < 4; i++) {
        int ra = wy * 64 + i * 16 + m;
        int sa = (ra << 3) + ((c * 4 + gg) ^ (ra & 7));
        ah[i] = as_bf(sAh[sa]);
        al[i] = as_bf(sAl[sa]);
      }
#pragma unroll
      for (int j = 0; j < 2; j++) {
        int rb = wx * 32 + j * 16 + m;
        int sb = (rb << 3) + ((c * 4 + gg) ^ (rb & 7));
        bh[j] = as_bf(sBh[sb]);
        bl[j] = as_bf(sBl[sb]);
      }
#pragma unroll
      for (int mi = 0; mi < 4; mi++)
#pragma unroll
        for (int ni = 0; ni < 2; ni++) {
          acc[mi][ni] = __builtin_amdgcn_mfma_f32_16x16x32_bf16(ah[mi], bh[ni], acc[mi][ni], 0, 0, 0);
          acc[mi][ni] = __builtin_amdgcn_mfma_f32_16x16x32_bf16(ah[mi], bl[ni], acc[mi][ni], 0, 0, 0);
          acc[mi][ni] = __builtin_amdgcn_mfma_f32_16x16x32_bf16(al[mi], bh[ni], acc[mi][ni], 0, 0, 0);
        }
    }
  }

#pragma unroll
  for (int ni = 0; ni < 2; ni++) {
    int l = lTile + wx * 32 + ni * 16 + m;
    float sc = scale[b * 1024 + l];
#pragma unroll
    for (int mi = 0; mi < 4; mi++) {
      int q0 = qTile + wy * 64 + mi * 16 + gg * 4;
#pragma unroll
      for (int r = 0; r < 4; r++)
        S[((size_t)b * 1024 + q0 + r) * 1024 + l] = acc[mi][ni][r] * sc;
    }
  }
}

// softmax over l, *mm, emit hi/lo bf16 probs
__global__ void softmax_rows_bf(const float* __restrict__ S, const float* __restrict__ mm,
                                ushort* __restrict__ Shi, ushort* __restrict__ Slo) {
  int q = blockIdx.x, b = blockIdx.y;
  const float* row = S + ((size_t)b * 1024 + q) * 1024;
  int tid = threadIdx.x;
  float v[4];
  float mx = -1e30f;
  for (int i = 0; i < 4; i++) { v[i] = row[tid + i * 256]; mx = fmaxf(mx, v[i]); }
  __shared__ float red[256];
  red[tid] = mx; __syncthreads();
  for (int s = 128; s > 0; s >>= 1) { if (tid < s) red[tid] = fmaxf(red[tid], red[tid + s]); __syncthreads(); }
  mx = red[0]; __syncthreads();
  float sum = 0.f;
  for (int i = 0; i < 4; i++) { v[i] = expf(10.f * (v[i] - mx)); sum += v[i]; }
  red[tid] = sum; __syncthreads();
  for (int s = 128; s > 0; s >>= 1) { if (tid < s) red[tid] += red[tid + s]; __syncthreads(); }
  sum = red[0];
  float inv = 1.f / sum;
  for (int i = 0; i < 4; i++) {
    int l = tid + i * 256;
    float p = v[i] * inv * mm[b * 1024 + l];
    ushort h = f2bf(p);
    size_t o = ((size_t)b * 1024 + q) * 1024 + l;
    Shi[o] = h;
    Slo[o] = f2bf(p - bf2f(h));
  }
}

// ---------------- cp2 prepW: block per (u,li); p = (u*16+v)*24 + c ----------
__global__ __launch_bounds__(256) void k_prepW(
    const ushort* __restrict__ t16H,
    ushort* __restrict__ WtH, int b) {
  int u = blockIdx.x >> 5, li = blockIdx.x & 31;
  int row = 8 * li + u - 4;
  bool rv = (row >= 0 && row < 256);
  __shared__ ushort sH[256 * 24];
  int tid = threadIdx.x;
  for (int t = tid; t < 768; t += 256) {
    uint4 h = {0u, 0u, 0u, 0u};
    if (rv) h = *(const uint4*)&t16H[((size_t)b * 65536 + (row << 8)) * 24 + t * 8];
    ((uint4*)sH)[t] = h;
  }
  __syncthreads();
  for (int pr = tid; pr < 384; pr += 256) {
    int v = pr / 24, c = pr - (pr / 24) * 24;
    int p = (u * 16 + v) * 24 + c;
    union { ushort us[32]; uint4 q[4]; } oh;
#pragma unroll 8
    for (int lj = 0; lj < 32; lj++) {
      int col = 8 * lj + v - 4;
      oh.us[lj] = (col >= 0 && col < 256) ? sH[col * 24 + c] : (ushort)0;
    }
    size_t o = (size_t)p * 1024 + li * 32;
#pragma unroll
    for (int g = 0; g < 4; g++) *(uint4*)&WtH[o + g * 8] = oh.q[g];
  }
}

// ---------------- MFMA GEMM cp2: TQ128 x TP256, K-chunk 64, 512 thr ---------
__global__ __launch_bounds__(512) void gemm_cp2_mfma(
    const ushort* __restrict__ Shi, const ushort* __restrict__ Slo,
    const ushort* __restrict__ Wthi,
    float* __restrict__ contrib, int b) {
  int f = blockIdx.x + blockIdx.y * 24;      // grid (24,8)
  int qTile = (f & 7) * 128, pTile = (f >> 3) * 256;  // same qTile -> same XCD
  __shared__ uint4 sAh[1024], sAl[1024], sBh[2048];

  int tid = threadIdx.x;
  int lane = tid & 63, w = tid >> 6;
  int wy = w >> 2, wx = w & 3;
  int m = lane & 15, gg = lane >> 4;

  f32x4 acc[4][4];
#pragma unroll
  for (int i = 0; i < 4; i++)
#pragma unroll
    for (int j = 0; j < 4; j++) acc[i][j] = (f32x4){0.f, 0.f, 0.f, 0.f};

  for (int l0 = 0; l0 < 1024; l0 += 64) {
    __syncthreads();
    for (int t = tid; t < 1024; t += 512) {
      int r = t >> 3, g = t & 7;
      int slot = (r << 3) + (g ^ (r & 7));
      size_t aoff = ((size_t)(b * 1024 + qTile + r)) * 1024 + l0;
      sAh[slot] = ((const uint4*)(Shi + aoff))[g];
      sAl[slot] = ((const uint4*)(Slo + aoff))[g];
    }
    for (int t = tid; t < 2048; t += 512) {
      int r = t >> 3, g = t & 7;
      int slot = (r << 3) + (g ^ (r & 7));
      size_t boff = ((size_t)(pTile + r)) * 1024 + l0;
      sBh[slot] = ((const uint4*)(Wthi + boff))[g];
    }
    __syncthreads();
#pragma unroll
    for (int c = 0; c < 2; c++) {
      bf16x8 ah[4], al[4], bh[4];
#pragma unroll
      for (int i = 0; i < 4; i++) {
        int ra = wy * 64 + i * 16 + m;
        int sa = (ra << 3) + ((c * 4 + gg) ^ (ra & 7));
        ah[i] = as_bf(sAh[sa]);
        al[i] = as_bf(sAl[sa]);
      }
#pragma unroll
      for (int j = 0; j < 4; j++) {
        int rb = wx * 64 + j * 16 + m;
        int sb = (rb << 3) + ((c * 4 + gg) ^ (rb & 7));
        bh[j] = as_bf(sBh[sb]);
      }
#pragma unroll
      for (int mi = 0; mi < 4; mi++)
#pragma unroll
        for (int ni = 0; ni < 4; ni++) {
          acc[mi][ni] = __builtin_amdgcn_mfma_f32_16x16x32_bf16(ah[mi], bh[ni], acc[mi][ni], 0, 0, 0);
          acc[mi][ni] = __builtin_amdgcn_mfma_f32_16x16x32_bf16(al[mi], bh[ni], acc[mi][ni], 0, 0, 0);
        }
    }
  }

#pragma unroll
  for (int ni = 0; ni < 4; ni++) {
    int p = pTile + wx * 64 + ni * 16 + m;
#pragma unroll
    for (int mi = 0; mi < 4; mi++) {
      int q0 = qTile + wy * 64 + mi * 16 + gg * 4;
#pragma unroll
      for (int r = 0; r < 4; r++)
        contrib[(size_t)(q0 + r) * 6144 + p] = acc[mi][ni][r];
    }
  }
}

// fold + blend; contrib p=(u*16+v)*24+c; thread per pixel, 24ch vectorized
__global__ void k_fold(const float* __restrict__ contrib,
                       const ushort* __restrict__ t16H, const ushort* __restrict__ t16L,
                       const float* __restrict__ mask,
                       ushort* __restrict__ outH, ushort* __restrict__ outL, int b) {
  int r = blockIdx.x * 256 + threadIdx.x;
  if (r >= 65536) return;
  int Y = r >> 8, X = r & 255;
  int yp = Y + 4, xp = X + 4;
  int qis[2], qjs[2];
  int cy = 0, cx = 0;
  int qi1 = yp >> 3;
  if (qi1 - 1 >= 0) qis[cy++] = qi1 - 1;
  if (qi1 < 32) qis[cy++] = qi1;
  int qj1 = xp >> 3;
  if (qj1 - 1 >= 0) qjs[cx++] = qj1 - 1;
  if (qj1 < 32) qjs[cx++] = qj1;
  float sum[24];
#pragma unroll
  for (int c = 0; c < 24; c++) sum[c] = 0.f;
  for (int a = 0; a < cy; a++)
    for (int d = 0; d < cx; d++) {
      int qi = qis[a], qj = qjs[d];
      int u = yp - 8 * qi, v = xp - 8 * qj;
      const float4* cp = (const float4*)&contrib[(size_t)(qi * 32 + qj) * 6144 + (u * 16 + v) * 24];
#pragma unroll
      for (int g = 0; g < 6; g++) {
        float4 f = cp[g];
        sum[g * 4 + 0] += f.x;
        sum[g * 4 + 1] += f.y;
        sum[g * 4 + 2] += f.z;
        sum[g * 4 + 3] += f.w;
      }
    }
  float inv = 1.f / (float)(cy * cx);
  float m = mask[(size_t)b * 65536 + r];
  size_t a16 = ((size_t)b * 65536 + r) * 24;
#pragma unroll
  for (int g = 0; g < 3; g++) {
    union { uint4 v; ushort u[8]; } th, tl, oh, ol;
    th.v = *(const uint4*)&t16H[a16 + g * 8];
    tl.v = *(const uint4*)&t16L[a16 + g * 8];
#pragma unroll
    for (int j = 0; j < 8; j++) {
      float base = bf2f(th.u[j]) + bf2f(tl.u[j]);
      float res = sum[g * 8 + j] * inv * m + base * (1.f - m);
      ushort h = f2bf(res);
      oh.u[j] = h;
      ol.u[j] = f2bf(res - bf2f(h));
    }
    *(uint4*)&outH[a16 + g * 8] = oh.v;
    *(uint4*)&outL[a16 + g * 8] = ol.v;
  }
}

// ---------------- launch ----------------
extern "C" void kernel_launch(void* const* d_in, const int* in_sizes, int n_in,
                              void* d_out, int out_size, void* d_ws, size_t ws_size,
                              hipStream_t stream) {
  const float* x      = (const float*)d_in[0];
  const float* mask   = (const float*)d_in[1];
  const float* x_st1  = (const float*)d_in[2];
  const float* x_st2  = (const float*)d_in[3];
  const float* pm     = (const float*)d_in[4];
  const float* b_sconv1 = (const float*)d_in[6];
  const float* b_sconv2 = (const float*)d_in[8];
  const float* b_bconv1 = (const float*)d_in[10];
  const float* b_bconv2 = (const float*)d_in[12];
  const float* b_bconv3 = (const float*)d_in[14];
  const float* b_bconv4 = (const float*)d_in[16];
  const float* b_conv13 = (const float*)d_in[18];
  const float* b_conv14 = (const float*)d_in[20];
  const float* b_conv15 = (const float*)d_in[22];
  const float* b_conv16 = (const float*)d_in[24];
  const float* b_conv16_2 = (const float*)d_in[26];
  const float* b_conv17 = (const float*)d_in[28];
  float* out = (float*)d_out;
  float* ws = (float*)d_ws;
  (void)in_sizes; (void)n_in; (void)out_size; (void)ws_size;

  // workspace layout (float offsets)
  const size_t o_masks  = 0;         // 16384
  const size_t o_mm     = 16384;     // 4096
  const size_t o_scale  = 20480;     // 4096
  const size_t o_xnowH  = 24576;     // 1048576
  const size_t o_xnowL  = 1073152;   // 1048576
  const size_t o_pmH    = 2121728;   // 786432
  const size_t o_pmL    = 2908160;   // 786432
  const size_t o_xsH    = 3694592;   // 786432
  const size_t o_xsL    = 4481024;   // 786432
  const size_t o_xsimH  = 5267456;   // 786432
  const size_t o_xsimL  = 6053888;   // 786432
  const size_t o_Phi    = 6840320;   // 3145728
  const size_t o_Plo    = 9986048;   // 3145728
  const size_t o_S      = 13131776;  // 4194304
  const size_t o_Shi    = 17326080;  // 2097152
  const size_t o_Slo    = 19423232;  // 2097152
  const size_t o_skip1H = 21520384;  // 3145728
  const size_t o_skip1L = 24666112;  // 3145728
  const size_t o_t2H    = 27811840;  // 1572864
  const size_t o_t2L    = 29384704;  // 1572864
  const size_t o_skip2H = 30957568;  // 1572864
  const size_t o_skip2L = 32530432;  // 1572864
  const size_t o_t4H    = 34103296;  // 786432
  const size_t o_t4L    = 34889728;  // 786432
  const size_t o_t13H   = 35676160;  // 1572864
  const size_t o_t13L   = 37249024;  // 1572864
  const size_t o_wbH    = 38821888;  // 586240 (WTOTAL uint4)
  // reuse
  const size_t o_t14H = o_t2H, o_t14L = o_t2L;
  const size_t o_t15H = o_Phi, o_t15L = o_Plo;
  const size_t o_t16H = o_S;
  const size_t o_t16L = o_pmH;
  const size_t o_WtH  = o_t2H;              // spans t2H+t2L
  const size_t o_contrib = o_Phi;           // spans Phi+Plo (t15 consumed)
  const size_t o_cp2H = o_skip1H, o_cp2L = o_skip1L;
  const size_t o_t162H = o_Phi, o_t162L = o_Plo;

  ushort* xnowH = (ushort*)(ws + o_xnowH); ushort* xnowL = (ushort*)(ws + o_xnowL);
  ushort* pmH  = (ushort*)(ws + o_pmH);   ushort* pmL  = (ushort*)(ws + o_pmL);
  ushort* xsH  = (ushort*)(ws + o_xsH);   ushort* xsL  = (ushort*)(ws + o_xsL);
  ushort* xsimH= (ushort*)(ws + o_xsimH); ushort* xsimL= (ushort*)(ws + o_xsimL);
  ushort* Phi  = (ushort*)(ws + o_Phi);   ushort* Plo  = (ushort*)(ws + o_Plo);
  ushort* Shi  = (ushort*)(ws + o_Shi);   ushort* Slo  = (ushort*)(ws + o_Slo);
  ushort* skip1H=(ushort*)(ws + o_skip1H);ushort* skip1L=(ushort*)(ws + o_skip1L);
  ushort* t2H  = (ushort*)(ws + o_t2H);   ushort* t2L  = (ushort*)(ws + o_t2L);
  ushort* skip2H=(ushort*)(ws + o_skip2H);ushort* skip2L=(ushort*)(ws + o_skip2L);
  ushort* t4H  = (ushort*)(ws + o_t4H);   ushort* t4L  = (ushort*)(ws + o_t4L);
  ushort* t13H = (ushort*)(ws + o_t13H);  ushort* t13L = (ushort*)(ws + o_t13L);
  ushort* t14H = (ushort*)(ws + o_t14H);  ushort* t14L = (ushort*)(ws + o_t14L);
  ushort* t15H = (ushort*)(ws + o_t15H);  ushort* t15L = (ushort*)(ws + o_t15L);
  ushort* t16H = (ushort*)(ws + o_t16H);  ushort* t16L = (ushort*)(ws + o_t16L);
  ushort* WtH  = (ushort*)(ws + o_WtH);
  ushort* cp2H = (ushort*)(ws + o_cp2H);  ushort* cp2L = (ushort*)(ws + o_cp2L);
  ushort* t162H= (ushort*)(ws + o_t162H); ushort* t162L= (ushort*)(ws + o_t162L);
  uint4* wbH = (uint4*)(ws + o_wbH);

  // layer offsets in uint4 units (order: sconv1,sconv2,bconv1..4,conv13..17)
  const size_t LOFF[12] = {0, 64512, 87552, 89344, 92800, 98560,
                           112384, 123904, 135424, 139264, 143104, 145408};

  WPtrs wp;
  wp.w[0] = (const float*)d_in[5];   wp.w[1] = (const float*)d_in[7];
  wp.w[2] = (const float*)d_in[9];   wp.w[3] = (const float*)d_in[11];
  wp.w[4] = (const float*)d_in[13];  wp.w[5] = (const float*)d_in[15];
  wp.w[6] = (const float*)d_in[17];  wp.w[7] = (const float*)d_in[19];
  wp.w[8] = (const float*)d_in[21];  wp.w[9] = (const float*)d_in[23];
  wp.w[10] = (const float*)d_in[25]; wp.w[11] = (const float*)d_in[27];
  prep_w_all<<<128, 256, 0, stream>>>(wp, wbH);

  // outputs 0,1: pass-through copies
  hipMemcpyAsync(out, x_st1, (size_t)786432 * 4, hipMemcpyDeviceToDevice, stream);
  hipMemcpyAsync(out + 786432, x_st2, (size_t)786432 * 4, hipMemcpyDeviceToDevice, stream);

  k_xnow<<<1024, 256, 0, stream>>>(x, x_st2, mask, xnowH, xnowL);
  k_tr<<<64, 256, 0, stream>>>(pm, pmH, pmL);

  // similarity branch
  conv_mfma<5, 1, 0, 8, 16, 16, 28><<<dim3(16, 6, BB), 256, 0, stream>>>(
      pmH, pmL, nullptr, nullptr, 96, 0, 12, 96, wbH + LOFF[0], b_sconv1,
      xsH, xsL, nullptr, 64, 64, 64, 64, 96, 96, 0, 4);
  conv_mfma<3, 1, 0, 16, 16, 16, 10><<<dim3(16, 6, BB), 256, 0, stream>>>(
      xsH, xsL, nullptr, nullptr, 96, 0, 12, 96, wbH + LOFF[1], b_sconv2,
      xsimH, xsimL, nullptr, 64, 64, 64, 64, 96, 96, 1, 4);
  k_mask_s<<<64, 256, 0, stream>>>(mask, ws + o_masks);
  k_mm<<<16, 256, 0, stream>>>(ws + o_masks, ws + o_mm);
  extract_patches_bf<<<4096, 256, 0, stream>>>(xsimH, xsimL, Phi, Plo);
  k_scale_bf<<<4096, 256, 0, stream>>>(Phi, Plo, ws + o_mm, ws + o_scale);
  gemm_qk_mfma<<<dim3(8, 8, BB), 512, 0, stream>>>(Phi, Plo, ws + o_scale, ws + o_S);
  softmax_rows_bf<<<dim3(1024, BB), 256, 0, stream>>>(ws + o_S, ws + o_mm, Shi, Slo);

  // main branch
  conv_mfma<5, 1, 0, 8, 16, 16, 28><<<dim3(256, 2, BB), 256, 0, stream>>>(
      xnowH, xnowL, nullptr, nullptr, 8, 0, 1, 8, wbH + LOFF[2], b_bconv1,
      skip1H, skip1L, nullptr, 256, 256, 256, 256, 24, 24, 0, 16);
  conv_mfma<3, 2, 0, 8, 8, 16, 12><<<dim3(128, 3, BB), 256, 0, stream>>>(
      skip1H, skip1L, nullptr, nullptr, 24, 0, 3, 24, wbH + LOFF[3], b_bconv2,
      t2H, t2L, nullptr, 256, 256, 128, 128, 48, 48, 0, 8);
  conv_mfma<3, 1, 0, 16, 16, 16, 10><<<dim3(64, 3, BB), 256, 0, stream>>>(
      t2H, t2L, nullptr, nullptr, 48, 0, 6, 48, wbH + LOFF[4], b_bconv3,
      skip2H, skip2L, nullptr, 128, 128, 128, 128, 48, 48, 0, 8);
  conv_mfma<3, 2, 0, 8, 8, 16, 12><<<dim3(32, 6, BB), 256, 0, stream>>>(
      skip2H, skip2L, nullptr, nullptr, 48, 0, 6, 48, wbH + LOFF[5], b_bconv4,
      t4H, t4L, nullptr, 128, 128, 64, 64, 96, 96, 0, 4);
  conv_mfma<3, 1, 1, 16, 16, 16, 10><<<dim3(64, 3, BB), 256, 0, stream>>>(
      t4H, t4L, nullptr, nullptr, 96, 0, 12, 96, wbH + LOFF[6], b_conv13,
      t13H, t13L, nullptr, 64, 64, 128, 128, 48, 48, 0, 8);
  conv_mfma<3, 1, 0, 16, 16, 16, 10><<<dim3(64, 3, BB), 256, 0, stream>>>(
      t13H, t13L, skip2H, skip2L, 48, 48, 6, 96, wbH + LOFF[7], b_conv14,
      t14H, t14L, nullptr, 128, 128, 128, 128, 48, 48, 0, 8);
  conv_mfma<3, 1, 1, 16, 16, 16, 10><<<dim3(256, 2, BB), 256, 0, stream>>>(
      t14H, t14L, nullptr, nullptr, 48, 0, 6, 48, wbH + LOFF[8], b_conv15,
      t15H, t15L, nullptr, 128, 128, 256, 256, 24, 24, 0, 16);
  conv_mfma<3, 1, 0, 16, 16, 16, 10><<<dim3(256, 2, BB), 256, 0, stream>>>(
      t15H, t15L, skip1H, skip1L, 24, 24, 3, 48, wbH + LOFF[9], b_conv16,
      t16H, t16L, nullptr, 256, 256, 256, 256, 24, 24, 0, 16);

  // cp2: per-batch prepW + MFMA GEMM + fold
  for (int b = 0; b < BB; b++) {
    k_prepW<<<512, 256, 0, stream>>>(t16H, WtH, b);
    gemm_cp2_mfma<<<dim3(24, 8), 512, 0, stream>>>(Shi, Slo, WtH, ws + o_contrib, b);
    k_fold<<<256, 256, 0, stream>>>(ws + o_contrib, t16H, t16L, mask, cp2H, cp2L, b);
  }

  // tail convs (cinp=24 -> CC=8 variant)
  conv_mfma<3, 1, 0, 8, 16, 16, 12><<<dim3(256, 2, BB), 256, 0, stream>>>(
      cp2H, cp2L, nullptr, nullptr, 24, 0, 3, 24, wbH + LOFF[10], b_conv16_2,
      t162H, t162L, nullptr, 256, 256, 256, 256, 24, 24, 0, 16);
  conv_mfma<3, 1, 0, 8, 16, 16, 12><<<dim3(256, 1, BB), 256, 0, stream>>>(
      t162H, t162L, nullptr, nullptr, 24, 0, 3, 24, wbH + LOFF[11], b_conv17,
      nullptr, nullptr, out + 2 * 786432, 256, 256, 256, 256, 3, 24, 2, 16);
}